// Round 8
// baseline (336.401 us; speedup 1.0000x reference)
//
#include <hip/hip_runtime.h>

#define H_   256
#define W_   256
#define HW_  65536
#define C_   256
#define MID  16
#define B_   2

// ---------------------------------------------------------------------------
// K0: 4 normalized anisotropic Gaussian 7x7 kernels (196 floats).
// ---------------------------------------------------------------------------
__global__ __launch_bounds__(256) void k0_prep(float* __restrict__ base_out) {
    __shared__ float s_k[4][49];
    __shared__ float s_inv[4];
    int t = threadIdx.x;
    if (t < 196) {
        int k = t / 49, p = t % 49;
        int i = p / 7, j = p % 7;
        float xx = (float)(i - 3), yy = (float)(j - 3);
        const float cs[4] = {1.0f, 0.70710678118654752f, 0.0f, -0.70710678118654752f};
        const float sn[4] = {0.0f, 0.70710678118654752f, 1.0f, 0.70710678118654752f};
        float c = cs[k], s = sn[k];
        float xr = xx * c + yy * s;
        float yr = -xx * s + yy * c;
        float v = expf(-(xr * xr * 0.08f + yr * yr * 0.5f));
        s_k[k][p] = v;
    }
    __syncthreads();
    if (t < 4) {
        float s = 0.f;
        for (int p = 0; p < 49; ++p) s += s_k[t][p];
        s_inv[t] = 1.0f / s;
    }
    __syncthreads();
    if (t < 196) base_out[t] = s_k[t / 49][t % 49] * s_inv[t / 49];
}

// ---------------------------------------------------------------------------
// kA: x_low planar [b][m][hw] = sum_c x[b,c,h,w] * rw[m][c].
// 512 blocks (b,h) x 256 thr (w) = 8 waves/CU. __launch_bounds__(256,2)
// gives a 256-VGPR budget so the 16-deep dword load pipeline stays in
// registers (round-3 failure: default bounds -> 36 VGPR -> 4-deep -> 670GB/s).
// 16 loads x 64 lanes x 4B x 8 waves = 32 KB/CU in flight >> 9.2 KB needed
// for HBM peak. Weights via uniform s_loads.
// ---------------------------------------------------------------------------
__global__ __launch_bounds__(256, 2) void kA_reduce(const float* __restrict__ x,
                                                    const float* __restrict__ rw,
                                                    float* __restrict__ xlow) {
    int bh = blockIdx.x;
    int b = bh >> 8, h = bh & 255;
    int w = threadIdx.x;
    const float* xp = x + (size_t)b * C_ * HW_ + h * W_ + w;
    float acc[MID];
#pragma unroll
    for (int m = 0; m < MID; ++m) acc[m] = 0.f;
    for (int cb = 0; cb < C_; cb += 16) {
        float xv[16];
#pragma unroll
        for (int i = 0; i < 16; ++i)
            xv[i] = xp[(size_t)(cb + i) * HW_];
#pragma unroll
        for (int i = 0; i < 16; ++i) {
#pragma unroll
            for (int m = 0; m < MID; ++m)
                acc[m] = fmaf(rw[m * C_ + cb + i], xv[i], acc[m]);
        }
    }
    float* op = xlow + (size_t)b * MID * HW_ + h * W_ + w;
#pragma unroll
    for (int m = 0; m < MID; ++m) op[(size_t)m * HW_] = acc[m];
}

// ---------------------------------------------------------------------------
// kB: per-pixel MLP -> softmax -> 49 blended taps e[7][7] in REGISTERS ->
// conv over 8 planar channels (m-half per block) -> olow px-major.
// 1024 blocks = b(2) x h(256) x mh(2) -> 16 waves/CU (4/SIMD).
// launch_bounds(256,4): <=128 VGPR, need ~90 (e:49, acc:8, cc:7, addr).
// m-outer loop => 49 independent L1-resident loads per plane, deeply batched.
// ---------------------------------------------------------------------------
__global__ __launch_bounds__(256, 4) void kB_conv(const float* __restrict__ xlow,
                                                  const float* __restrict__ base,
                                                  const float* __restrict__ angle,
                                                  const float* __restrict__ w1,
                                                  const float* __restrict__ b1,
                                                  const float* __restrict__ w2,
                                                  const float* __restrict__ b2,
                                                  float* __restrict__ olow) {
    int bid = blockIdx.x;
    int mh = bid & 1;
    int h = (bid >> 1) & 255;
    int b = bid >> 9;
    int w = threadIdx.x;

    // ---- MLP + softmax -> wk[4] ----
    float a2 = 2.0f * angle[(size_t)b * HW_ + h * W_ + w];
    float f0 = __sinf(a2), f1 = __cosf(a2);
    float hb[8];
#pragma unroll
    for (int j = 0; j < 8; ++j)
        hb[j] = fmaxf(fmaf(w1[j * 2], f0, fmaf(w1[j * 2 + 1], f1, b1[j])), 0.f);
    float lg[4];
#pragma unroll
    for (int k = 0; k < 4; ++k) {
        float s = b2[k];
#pragma unroll
        for (int j = 0; j < 8; ++j) s = fmaf(w2[k * 8 + j], hb[j], s);
        lg[k] = s;
    }
    float mx = fmaxf(fmaxf(lg[0], lg[1]), fmaxf(lg[2], lg[3]));
    float wk[4];
    float ssum = 0.f;
#pragma unroll
    for (int k = 0; k < 4; ++k) { wk[k] = __expf(lg[k] - mx); ssum += wk[k]; }
    float inv = 1.0f / ssum;
#pragma unroll
    for (int k = 0; k < 4; ++k) wk[k] *= inv;

    // ---- blended taps into registers (uniform base -> s_loads) ----
    float e[49];
#pragma unroll
    for (int tp = 0; tp < 49; ++tp)
        e[tp] = fmaf(wk[0], base[tp],
                fmaf(wk[1], base[49 + tp],
                fmaf(wk[2], base[98 + tp], wk[3] * base[147 + tp])));

    // ---- reflect indices ----
    int cc[7];
#pragma unroll
    for (int dx = 0; dx < 7; ++dx) {
        int c0 = w + dx - 3;
        cc[dx] = c0 < 0 ? -c0 : (c0 > 255 ? 510 - c0 : c0);
    }
    int rr[7];
#pragma unroll
    for (int dy = 0; dy < 7; ++dy) {
        int hy = h + dy - 3;
        rr[dy] = (hy < 0 ? -hy : (hy > 255 ? 510 - hy : hy)) * W_;
    }

    // ---- conv: 8 planes, m-outer, 49 independent loads per plane ----
    const float* xb = xlow + (size_t)b * MID * HW_ + (size_t)mh * 8 * HW_;
    float acc[8];
#pragma unroll
    for (int m = 0; m < 8; ++m) {
        const float* pm = xb + (size_t)m * HW_;
        float s = 0.f;
#pragma unroll
        for (int dy = 0; dy < 7; ++dy) {
            const float* r = pm + rr[dy];
#pragma unroll
            for (int dx = 0; dx < 7; ++dx)
                s = fmaf(e[dy * 7 + dx], r[cc[dx]], s);
        }
        acc[m] = s;
    }

    float4* op = (float4*)(olow + ((size_t)b * HW_ + h * W_ + w) * MID + mh * 8);
    op[0] = make_float4(acc[0], acc[1], acc[2], acc[3]);
    op[1] = make_float4(acc[4], acc[5], acc[6], acc[7]);
}

// ---------------------------------------------------------------------------
// kC: expand 16->256, c-split 4 -> 2048 blocks = 32 waves/CU, write-stream.
// ---------------------------------------------------------------------------
__global__ __launch_bounds__(256) void kC_expand(const float* __restrict__ olow,
                                                 const float* __restrict__ ew,
                                                 float* __restrict__ out) {
    int bid = blockIdx.x;
    int cq = bid & 3;
    int h = (bid >> 2) & 255;
    int b = bid >> 10;
    int w = threadIdx.x;
    const float4* ip = (const float4*)(olow + ((size_t)b * HW_ + h * W_ + w) * MID);
    float4 m0 = ip[0], m1 = ip[1], m2 = ip[2], m3 = ip[3];
    float* ob = out + ((size_t)b * C_ + cq * 64) * HW_ + h * W_ + w;
    const float* wb = ew + (size_t)cq * 64 * MID;
#pragma unroll 8
    for (int ci = 0; ci < 64; ++ci) {
        const float* wc = wb + ci * MID;
        float s;
        s = wc[0] * m0.x;
        s = fmaf(wc[1], m0.y, s);
        s = fmaf(wc[2], m0.z, s);
        s = fmaf(wc[3], m0.w, s);
        s = fmaf(wc[4], m1.x, s);
        s = fmaf(wc[5], m1.y, s);
        s = fmaf(wc[6], m1.z, s);
        s = fmaf(wc[7], m1.w, s);
        s = fmaf(wc[8], m2.x, s);
        s = fmaf(wc[9], m2.y, s);
        s = fmaf(wc[10], m2.z, s);
        s = fmaf(wc[11], m2.w, s);
        s = fmaf(wc[12], m3.x, s);
        s = fmaf(wc[13], m3.y, s);
        s = fmaf(wc[14], m3.z, s);
        s = fmaf(wc[15], m3.w, s);
        __builtin_nontemporal_store(s, ob + (size_t)ci * HW_);
    }
}

// ---------------------------------------------------------------------------
extern "C" void kernel_launch(void* const* d_in, const int* in_sizes, int n_in,
                              void* d_out, int out_size, void* d_ws, size_t ws_size,
                              hipStream_t stream) {
    const float* x     = (const float*)d_in[0];
    const float* angle = (const float*)d_in[1];
    const float* rw    = (const float*)d_in[2];
    const float* ew    = (const float*)d_in[3];
    const float* w1    = (const float*)d_in[4];
    const float* b1    = (const float*)d_in[5];
    const float* w2    = (const float*)d_in[6];
    const float* b2    = (const float*)d_in[7];
    float* out = (float*)d_out;

    float* wsf  = (float*)d_ws;
    float* base = wsf;                               // 196 floats
    float* xlow = wsf + 256;                         // 2M floats, planar
    float* olow = xlow + (size_t)B_ * MID * HW_;     // 2M floats, px-major

    hipLaunchKernelGGL(k0_prep,   dim3(1),    dim3(256), 0, stream, base);
    hipLaunchKernelGGL(kA_reduce, dim3(512),  dim3(256), 0, stream, x, rw, xlow);
    hipLaunchKernelGGL(kB_conv,   dim3(1024), dim3(256), 0, stream,
                       xlow, base, angle, w1, b1, w2, b2, olow);
    hipLaunchKernelGGL(kC_expand, dim3(2048), dim3(256), 0, stream, olow, ew, out);
}